// Round 20
// baseline (220.434 us; speedup 1.0000x reference)
//
#include <hip/hip_runtime.h>
#include <hip/hip_bf16.h>
#include <stdint.h>

#define DIN 2048
#define DEMB 1024
#define NSUP 2048
#define NQRY 16384
#define NWAY 64

typedef __attribute__((ext_vector_type(8))) short bf16x8;
typedef __attribute__((ext_vector_type(4))) float f32x4;

__device__ inline unsigned short f2bf(float f) {
    union { float f; uint32_t u; } v; v.f = f;
    uint32_t u = v.u;
    uint32_t r = (u + 0x7FFFu + ((u >> 16) & 1u)) >> 16;
    return (unsigned short)r;
}

#define GLL(g, l) __builtin_amdgcn_global_load_lds(                                   \
    (const __attribute__((address_space(1))) void*)(g),                               \
    (__attribute__((address_space(3))) void*)(l), 16, 0, 0)

// ================ prep: query cvt | support cvt | W transpose | zero accumulators ====
__global__ __launch_bounds__(256) void prep_kernel(
    const float* __restrict__ query, const float* __restrict__ support,
    const float* __restrict__ W,
    unsigned short* __restrict__ q_bf, unsigned short* __restrict__ s_bf,
    unsigned short* __restrict__ Wt,
    float* __restrict__ proto_sums, float* __restrict__ qsq)
{
    __shared__ float tile[32][33];
    const int b = blockIdx.x;
    if (b < 2048) {                       // query f32 -> bf16 (33.5M elems)
        int i = (b * 256 + threadIdx.x) * 4;
        const int stride = 2048 * 256 * 4;
        for (; i < NQRY * DIN; i += stride) {
            float4 v = *(const float4*)(query + i);
            ushort4 o;
            o.x = f2bf(v.x); o.y = f2bf(v.y); o.z = f2bf(v.z); o.w = f2bf(v.w);
            *(ushort4*)(q_bf + i) = o;
        }
    } else if (b < 2560) {                // support f32 -> bf16 (4.2M elems)
        int i = ((b - 2048) * 256 + threadIdx.x) * 4;
        const int stride = 512 * 256 * 4;
        for (; i < NSUP * DIN; i += stride) {
            float4 v = *(const float4*)(support + i);
            ushort4 o;
            o.x = f2bf(v.x); o.y = f2bf(v.y); o.z = f2bf(v.z); o.w = f2bf(v.w);
            *(ushort4*)(s_bf + i) = o;
        }
    } else if (b < 4608) {                // W [DIN][DEMB] f32 -> Wt [DEMB][DIN] bf16
        const int bb = b - 2560;
        const int c0 = (bb & 31) * 32, r0 = (bb >> 5) * 32;
        const int tc = threadIdx.x & 31, tr = threadIdx.x >> 5;
        #pragma unroll
        for (int i = 0; i < 4; i++)
            tile[tr + 8*i][tc] = W[(size_t)(r0 + tr + 8*i) * DEMB + c0 + tc];
        __syncthreads();
        #pragma unroll
        for (int i = 0; i < 4; i++)
            Wt[(size_t)(c0 + tr + 8*i) * DIN + r0 + tc] = f2bf(tile[tc][tr + 8*i]);
    } else {                              // zero proto_sums (65536 f) + qsq (16384 f)
        const int off = ((b - 4608) * 256 + threadIdx.x) * 4;
        float4 z = { 0.f, 0.f, 0.f, 0.f };
        if (off < NWAY * DEMB) *(float4*)(proto_sums + off) = z;
        else                   *(float4*)(qsq + off - NWAY * DEMB) = z;
    }
}

// ================ query GEMM: 256x256, BK=64, 8-wave, 8-PHASE + FUSED SCORES =========
// Main loop byte-identical to r17/r18 (verified 108us, absmax 0.25).
// Epilogue: E -> per-wave LDS region (bf16, kgrp-major) -> P = E x protoT (64 MFMA)
// -> deterministic 4-pass wc-reduction in LDS -> dots[bx][q][c] plain f32 stores.

#define SG_LO(la, g) { GLL((g), (la)); GLL((g) + 16, (la) + 4096); }
#define SG_HI(la, g) { GLL((g) + 32, (la) + 8192); GLL((g) + 48, (la) + 12288); }

#define READ_B(buf, ks)                                                                \
    _Pragma("unroll") for (int ni = 0; ni < 4; ++ni)                                   \
        bfm[ni] = *(const bf16x8*)&Bs[(buf) * 16384 + (ks) * 8192 + bbase + ni * 128];
#define READ_A(buf, ks, mh)                                                            \
    _Pragma("unroll") for (int mi = 0; mi < 4; ++mi)                                   \
        af[mi] = *(const bf16x8*)&As[(buf) * 16384 + (ks) * 8192 + abase + ((mh)*4 + mi) * 128];
#define MFMA16(mh)                                                                     \
    __builtin_amdgcn_s_setprio(1);                                                     \
    _Pragma("unroll") for (int mi = 0; mi < 4; ++mi)                                   \
        _Pragma("unroll") for (int ni = 0; ni < 4; ++ni)                               \
            acc[(mh)*4 + mi][ni] = __builtin_amdgcn_mfma_f32_16x16x32_bf16(            \
                af[mi], bfm[ni], acc[(mh)*4 + mi][ni], 0, 0, 0);                       \
    __builtin_amdgcn_s_setprio(0);

#define BAR1_LG() do { asm volatile("" ::: "memory"); __builtin_amdgcn_s_barrier();    \
    asm volatile("s_waitcnt lgkmcnt(0)" ::: "memory");                                 \
    __builtin_amdgcn_sched_barrier(0); } while (0)
#define BAR2() do { asm volatile("" ::: "memory"); __builtin_amdgcn_s_barrier();       \
    asm volatile("" ::: "memory"); } while (0)
#define BAR2_VM4() do { asm volatile("s_waitcnt vmcnt(4)" ::: "memory");               \
    __builtin_amdgcn_s_barrier(); asm volatile("" ::: "memory"); } while (0)
#define BAR2_VM0() do { asm volatile("s_waitcnt vmcnt(0)" ::: "memory");               \
    __builtin_amdgcn_s_barrier(); asm volatile("" ::: "memory"); } while (0)

__global__ __launch_bounds__(512) void gemm_query8(
    const unsigned short* __restrict__ A,
    const unsigned short* __restrict__ Bt,
    const float* __restrict__ bias,
    const unsigned short* __restrict__ protos,   // [NWAY][DEMB] bf16
    float* __restrict__ dots,                    // [4][NQRY][NWAY] f32
    float* __restrict__ qsq)
{
    __shared__ __attribute__((aligned(16))) unsigned short As[2 * 16384];
    __shared__ __attribute__((aligned(16))) unsigned short Bs[2 * 16384];

    const int tid = threadIdx.x;
    const int nblk = DEMB / 256;          // 4
    const int h = blockIdx.x;
    const int cpx = (int)(gridDim.x >> 3);
    const int wg = (h & 7) * cpx + (h >> 3);
    const int bx = wg % nblk, by = wg / nblk;
    const int brow = by * 256, bcol = bx * 256;
    const int lane = tid & 63, wid = tid >> 6;
    const int wr = wid >> 2, wc = wid & 3;

    const int rows = tid & 255, kg0 = tid >> 8;
    const unsigned short* gA = A  + (size_t)(brow + rows) * DIN + kg0 * 8;
    const unsigned short* gB = Bt + (size_t)(bcol + rows) * DIN + kg0 * 8;
    unsigned short* laA0 = As + tid * 8;
    unsigned short* laA1 = As + 16384 + tid * 8;
    unsigned short* laB0 = Bs + tid * 8;
    unsigned short* laB1 = Bs + 16384 + tid * 8;

    const int kgl = lane >> 4, r = lane & 15;
    const int abase = (kgl * 256 + wr * 128 + r) * 8;
    const int bbase = (kgl * 256 + wc * 64 + r) * 8;

    f32x4 acc[8][4];
    #pragma unroll
    for (int i = 0; i < 8; i++)
        #pragma unroll
        for (int j = 0; j < 4; j++) acc[i][j] = (f32x4)(0.f);

    SG_LO(laA0, gA); SG_LO(laB0, gB);
    SG_HI(laA0, gA); SG_HI(laB0, gB);
    asm volatile("s_waitcnt vmcnt(4)" ::: "memory");
    __builtin_amdgcn_s_barrier();
    asm volatile("" ::: "memory");

    const unsigned short* gA1 = gA + 64;
    const unsigned short* gB1 = gB + 64;
    const unsigned short* gA0 = gA + 128;
    const unsigned short* gB0 = gB + 128;

    bf16x8 af[4], bfm[4];

#define PH_ITER(LAST)                                                                  \
    READ_B(0, 0); READ_A(0, 0, 0); SG_LO(laA1, gA1); BAR1_LG(); MFMA16(0); BAR2();     \
    READ_A(0, 0, 1); SG_LO(laB1, gB1); BAR1_LG(); MFMA16(1); BAR2_VM4();               \
    READ_B(0, 1); READ_A(0, 1, 0); SG_HI(laA1, gA1); BAR1_LG(); MFMA16(0); BAR2();     \
    READ_A(0, 1, 1); SG_HI(laB1, gB1); BAR1_LG(); MFMA16(1); BAR2_VM4();               \
    READ_B(1, 0); READ_A(1, 0, 0);                                                     \
    if (!(LAST)) { SG_LO(laA0, gA0); }                                                 \
    BAR1_LG(); MFMA16(0); BAR2();                                                      \
    READ_A(1, 0, 1);                                                                   \
    if (!(LAST)) { SG_LO(laB0, gB0); }                                                 \
    BAR1_LG(); MFMA16(1);                                                              \
    if (LAST) { BAR2_VM0(); } else { BAR2_VM4(); }                                     \
    READ_B(1, 1); READ_A(1, 1, 0);                                                     \
    if (!(LAST)) { SG_HI(laA0, gA0); }                                                 \
    BAR1_LG(); MFMA16(0); BAR2();                                                      \
    READ_A(1, 1, 1);                                                                   \
    if (!(LAST)) { SG_HI(laB0, gB0); }                                                 \
    BAR1_LG(); MFMA16(1);                                                              \
    if (LAST) { BAR2(); } else { BAR2_VM4(); }

    #pragma unroll 1
    for (int it = 0; it < 15; ++it) {
        PH_ITER(false);
        gA1 += 128; gB1 += 128; gA0 += 128; gB0 += 128;
    }
    PH_ITER(true);
#undef PH_ITER

    // ===== fused-scores epilogue =====
    const int r16 = lane & 15, quad = lane >> 4;   // quad == kgl
    float bv[4];
    #pragma unroll
    for (int ni = 0; ni < 4; ni++) bv[ni] = bias[bcol + wc * 64 + ni * 16 + r16];

    // per-wave E region (128 rows x 64 k bf16, kgrp-major [kg8][128][8]), 16 KB.
    // Waves 0-3 -> As, waves 4-7 -> Bs. Own-region only: no barrier needed before
    // the P-MFMA reads (main-loop LDS reads all retired before the final barrier).
    unsigned short* Ew = (wid < 4 ? As : Bs) + (wid & 3) * 8192;
    const int kgE = r16 >> 3, elem = r16 & 7;

    #pragma unroll
    for (int mi = 0; mi < 8; mi++) {
        float s0 = 0.f, s1 = 0.f, s2 = 0.f, s3 = 0.f;
        #pragma unroll
        for (int j = 0; j < 4; j++) {
            int rowl = mi * 16 + quad * 4 + j;           // 0..127 within wave
            float sj = 0.f;
            #pragma unroll
            for (int ni = 0; ni < 4; ni++) {
                float e = acc[mi][ni][j] + bv[ni];
                Ew[((ni * 2 + kgE) * 128 + rowl) * 8 + elem] = f2bf(e);
                sj += e * e;
            }
            if (j == 0) s0 = sj; else if (j == 1) s1 = sj; else if (j == 2) s2 = sj; else s3 = sj;
        }
        float sv[4] = { s0, s1, s2, s3 };
        #pragma unroll
        for (int j = 0; j < 4; j++) {
            float v = sv[j];
            v += __shfl_xor(v, 1);
            v += __shfl_xor(v, 2);
            v += __shfl_xor(v, 4);
            v += __shfl_xor(v, 8);
            if (r16 == 0) {
                int row = brow + wr * 128 + mi * 16 + quad * 4 + j;
                atomicAdd(&qsq[row], v);
            }
        }
    }

    // P = E(128x64) @ protoT(64k x 64c): 64 MFMA/wave. B-frags straight from L2-hot
    // protos (same access pattern as the verified standalone scores kernel).
    f32x4 p2[8][4];
    #pragma unroll
    for (int i = 0; i < 8; i++)
        #pragma unroll
        for (int j = 0; j < 4; j++) p2[i][j] = (f32x4)(0.f);

    bf16x8 bp[4][2];
    #pragma unroll
    for (int ni = 0; ni < 4; ni++)
        #pragma unroll
        for (int ks = 0; ks < 2; ks++)
            bp[ni][ks] = *(const bf16x8*)(protos + (size_t)(ni * 16 + r16) * DEMB
                                          + bcol + wc * 64 + ks * 32 + quad * 8);
    #pragma unroll
    for (int mi = 0; mi < 8; mi++) {
        bf16x8 ea0 = *(const bf16x8*)&Ew[((0 * 4 + quad) * 128 + mi * 16 + r16) * 8];
        bf16x8 ea1 = *(const bf16x8*)&Ew[((1 * 4 + quad) * 128 + mi * 16 + r16) * 8];
        #pragma unroll
        for (int ni = 0; ni < 4; ni++) {
            p2[mi][ni] = __builtin_amdgcn_mfma_f32_16x16x32_bf16(ea0, bp[ni][0], p2[mi][ni], 0, 0, 0);
            p2[mi][ni] = __builtin_amdgcn_mfma_f32_16x16x32_bf16(ea1, bp[ni][1], p2[mi][ni], 0, 0, 0);
        }
    }

    // deterministic cross-wave (wc) reduction: sequential passes into Pl[256][64]
    asm volatile("" ::: "memory");
    __builtin_amdgcn_s_barrier();        // all P-MFMA LDS reads done; LDS free
    float* Pl = (float*)As;              // 256 x 64 f32 = 64 KB
    #pragma unroll 1
    for (int pass = 0; pass < 4; ++pass) {
        if (wc == pass) {
            #pragma unroll
            for (int mi = 0; mi < 8; mi++)
                #pragma unroll
                for (int j = 0; j < 4; j++)
                    #pragma unroll
                    for (int ni = 0; ni < 4; ni++) {
                        int idx = (wr * 128 + mi * 16 + quad * 4 + j) * 64 + ni * 16 + r16;
                        if (pass == 0) Pl[idx] = p2[mi][ni][j];
                        else           Pl[idx] += p2[mi][ni][j];
                    }
        }
        asm volatile("" ::: "memory");
        __builtin_amdgcn_s_barrier();
        asm volatile("" ::: "memory");
    }

    // dots[bx][brow+row][c], coalesced float4 (each cell written by exactly one block)
    float* drow = dots + ((size_t)bx * NQRY + brow) * NWAY;
    #pragma unroll
    for (int i = 0; i < 8; i++) {
        int off = (i * 512 + tid) * 4;
        *(float4*)(drow + off) = *(const float4*)(Pl + off);
    }
}

// ---------------- support GEMM: BM=64, BN=128, 3-buf single-barrier (r18, verified) ---
__global__ __launch_bounds__(256, 2) void gemm_support(
    const unsigned short* __restrict__ A,
    const unsigned short* __restrict__ Bt,
    const float* __restrict__ bias,
    const int* __restrict__ labels,
    float* __restrict__ proto_sums)
{
    constexpr int ASZ = 4 * 64 * 8;
    constexpr int BSZ = 4 * 128 * 8;
    __shared__ __attribute__((aligned(16))) unsigned short AsF[3 * ASZ];
    __shared__ __attribute__((aligned(16))) unsigned short BsF[3 * BSZ];

    const int tid = threadIdx.x;
    const int nblk = DEMB / 128;          // 8
    const int h = blockIdx.x;
    const int cpx = (int)(gridDim.x >> 3);
    const int wg = (h & 7) * cpx + (h >> 3);
    const int bx = wg % nblk, by = wg / nblk;
    const int brow = by * 64, bcol = bx * 128;
    const int lane = tid & 63, wid = tid >> 6;
    const int wc = wid;

    const unsigned short* ga = A  + (size_t)(brow + (tid & 63)) * DIN + (tid >> 6) * 8;
    const unsigned short* gb = Bt + (size_t)(bcol + (tid & 127)) * DIN + (tid >> 7) * 8;

    f32x4 acc[4][2];
    #pragma unroll
    for (int i = 0; i < 4; i++)
        #pragma unroll
        for (int j = 0; j < 2; j++) acc[i][j] = (f32x4)(0.f);

    auto stageAB = [&](int buf) {
        unsigned short* la = AsF + buf * ASZ + tid * 8;
        unsigned short* lb = BsF + buf * BSZ + tid * 8;
        GLL(ga, la);
        GLL(gb, lb); GLL(gb + 16, lb + 2048);
        ga += 32; gb += 32;
    };

    stageAB(0);

    const int kg = lane >> 4, r = lane & 15;
    const int NT = DIN / 32;   // 64
    int cur = 0, nxt = 1;
    for (int t = 0; t < NT; ++t) {
        if (t < NT - 1) {
            stageAB(nxt);
            asm volatile("s_waitcnt vmcnt(3)" ::: "memory");
        } else {
            asm volatile("s_waitcnt vmcnt(0)" ::: "memory");
        }
        __builtin_amdgcn_s_barrier();
        asm volatile("" ::: "memory");

        const unsigned short* Ab = AsF + cur * ASZ;
        const unsigned short* Bb = BsF + cur * BSZ;
        bf16x8 af[4], bfm[2];
        #pragma unroll
        for (int mi = 0; mi < 4; mi++)
            af[mi] = *(const bf16x8*)&Ab[(kg * 64 + mi * 16 + r) * 8];
        #pragma unroll
        for (int ni = 0; ni < 2; ni++)
            bfm[ni] = *(const bf16x8*)&Bb[(kg * 128 + wc * 32 + ni * 16 + r) * 8];
        __builtin_amdgcn_s_setprio(1);
        #pragma unroll
        for (int mi = 0; mi < 4; mi++)
            #pragma unroll
            for (int ni = 0; ni < 2; ni++)
                acc[mi][ni] = __builtin_amdgcn_mfma_f32_16x16x32_bf16(af[mi], bfm[ni], acc[mi][ni], 0, 0, 0);
        __builtin_amdgcn_s_setprio(0);
        asm volatile("" ::: "memory");

        cur = (cur == 2) ? 0 : cur + 1;
        nxt = (nxt == 2) ? 0 : nxt + 1;
    }

    const int r16 = lane & 15, quad = lane >> 4;
    float bv[2];
    #pragma unroll
    for (int ni = 0; ni < 2; ni++) bv[ni] = bias[bcol + wc * 32 + ni * 16 + r16];

    #pragma unroll
    for (int mi = 0; mi < 4; mi++) {
        #pragma unroll
        for (int j = 0; j < 4; j++) {
            int row = brow + mi * 16 + quad * 4 + j;
            int lab = labels[row];
            #pragma unroll
            for (int ni = 0; ni < 2; ni++) {
                float e = acc[mi][ni][j] + bv[ni];
                atomicAdd(&proto_sums[(size_t)lab * DEMB + bcol + wc * 32 + ni * 16 + r16], e);
            }
        }
    }
}

// ---------------- prototype normalize ----------------
__global__ void proto_norm(const float* __restrict__ proto_sums,
                           const int* __restrict__ labels,
                           unsigned short* __restrict__ proto_bf16,
                           float* __restrict__ psq) {
    int c = blockIdx.x;
    int tid = threadIdx.x;
    int cnt = 0;
    for (int i = tid; i < NSUP; i += 256) cnt += (labels[i] == c) ? 1 : 0;
    #pragma unroll
    for (int m = 1; m < 64; m <<= 1) cnt += __shfl_xor(cnt, m);
    __shared__ int warp_cnt[4];
    __shared__ float warp_ss[4];
    if ((tid & 63) == 0) warp_cnt[tid >> 6] = cnt;
    __syncthreads();
    int total = warp_cnt[0] + warp_cnt[1] + warp_cnt[2] + warp_cnt[3];
    float inv = 1.0f / (float)total;
    float ss = 0.f;
    for (int j = tid; j < DEMB; j += 256) {
        float p = proto_sums[(size_t)c * DEMB + j] * inv;
        proto_bf16[(size_t)c * DEMB + j] = f2bf(p);
        ss += p * p;
    }
    #pragma unroll
    for (int m = 1; m < 64; m <<= 1) ss += __shfl_xor(ss, m);
    if ((tid & 63) == 0) warp_ss[tid >> 6] = ss;
    __syncthreads();
    if (tid == 0) psq[c] = warp_ss[0] + warp_ss[1] + warp_ss[2] + warp_ss[3];
}

// ---------------- combine: out[q][c] = -sqrt(max(qsq+psq-2*sum(dots),0)) -------------
__global__ __launch_bounds__(256) void combine_kernel(
    const float* __restrict__ dots, const float* __restrict__ qsq,
    const float* __restrict__ psq, float* __restrict__ out)
{
    const int i4 = (blockIdx.x * 256 + threadIdx.x) * 4;   // 64 % 4 == 0: never crosses q
    const int q = i4 >> 6, c = i4 & 63;
    const size_t plane = (size_t)NQRY * NWAY;
    float4 d0 = *(const float4*)(dots + i4);
    float4 d1 = *(const float4*)(dots + plane + i4);
    float4 d2 = *(const float4*)(dots + 2 * plane + i4);
    float4 d3 = *(const float4*)(dots + 3 * plane + i4);
    const float qs = qsq[q];
    float4 r;
    r.x = -sqrtf(fmaxf(qs + psq[c + 0] - 2.f * (d0.x + d1.x + d2.x + d3.x), 0.f));
    r.y = -sqrtf(fmaxf(qs + psq[c + 1] - 2.f * (d0.y + d1.y + d2.y + d3.y), 0.f));
    r.z = -sqrtf(fmaxf(qs + psq[c + 2] - 2.f * (d0.z + d1.z + d2.z + d3.z), 0.f));
    r.w = -sqrtf(fmaxf(qs + psq[c + 3] - 2.f * (d0.w + d1.w + d2.w + d3.w), 0.f));
    *(float4*)(out + i4) = r;
}

// ---------------- launch ----------------
extern "C" void kernel_launch(void* const* d_in, const int* in_sizes, int n_in,
                              void* d_out, int out_size, void* d_ws, size_t ws_size,
                              hipStream_t stream) {
    const float* support = (const float*)d_in[0];
    const float* query   = (const float*)d_in[1];
    const int*   labels  = (const int*)d_in[2];
    // d_in[3] = n_way (assumed 64)
    const float* W       = (const float*)d_in[4];
    const float* bias    = (const float*)d_in[5];
    float* out = (float*)d_out;

    char* ws = (char*)d_ws;
    unsigned short* q_bf     = (unsigned short*)(ws);                 // 67108864 B
    unsigned short* s_bf     = (unsigned short*)(ws + 67108864);      //  8388608 B
    unsigned short* Wt       = (unsigned short*)(ws + 75497472);      //  4194304 B
    float*          dots     = (float*)(ws + 79691776);               // 16777216 B
    float*          proto_sums = (float*)(ws + 113246208);            //   262144 B
    unsigned short* proto_bf = (unsigned short*)(ws + 113508352);     //   131072 B
    float*          qsq      = (float*)(ws + 113639424);              //    65536 B
    float*          psq      = (float*)(ws + 113704960);              //      256 B

    // prep: [0,2048) query cvt | [2048,2560) support cvt | [2560,4608) W transpose
    //       | [4608,4688) zero proto_sums+qsq
    prep_kernel<<<4688, 256, 0, stream>>>(query, support, W, q_bf, s_bf, Wt,
                                          proto_sums, qsq);
    gemm_support<<<(NSUP / 64) * (DEMB / 128), 256, 0, stream>>>(
        s_bf, Wt, bias, labels, proto_sums);
    proto_norm<<<NWAY, 256, 0, stream>>>(proto_sums, labels, proto_bf, psq);
    gemm_query8<<<(NQRY / 256) * (DEMB / 256), 512, 0, stream>>>(
        q_bf, Wt, bias, proto_bf, dots, qsq);
    combine_kernel<<<NQRY * NWAY / 1024, 256, 0, stream>>>(dots, qsq, psq, out);
}

// Round 23
// 213.731 us; speedup vs baseline: 1.0314x; 1.0314x over previous
//
#include <hip/hip_runtime.h>
#include <hip/hip_bf16.h>
#include <stdint.h>

#define DIN 2048
#define DEMB 1024
#define NSUP 2048
#define NQRY 16384
#define NWAY 64

typedef __attribute__((ext_vector_type(8))) short bf16x8;
typedef __attribute__((ext_vector_type(4))) float f32x4;

__device__ inline unsigned short f2bf(float f) {
    union { float f; uint32_t u; } v; v.f = f;
    uint32_t u = v.u;
    uint32_t r = (u + 0x7FFFu + ((u >> 16) & 1u)) >> 16;
    return (unsigned short)r;
}

#define GLL(g, l) __builtin_amdgcn_global_load_lds(                                   \
    (const __attribute__((address_space(1))) void*)(g),                               \
    (__attribute__((address_space(3))) void*)(l), 16, 0, 0)

// ================ prep: query cvt | support cvt | W transpose | zero accumulators ====
__global__ __launch_bounds__(256) void prep_kernel(
    const float* __restrict__ query, const float* __restrict__ support,
    const float* __restrict__ W,
    unsigned short* __restrict__ q_bf, unsigned short* __restrict__ s_bf,
    unsigned short* __restrict__ Wt,
    float* __restrict__ proto_sums, float* __restrict__ qsq)
{
    __shared__ float tile[32][33];
    const int b = blockIdx.x;
    if (b < 2048) {                       // query f32 -> bf16 (33.5M elems)
        int i = (b * 256 + threadIdx.x) * 4;
        const int stride = 2048 * 256 * 4;
        for (; i < NQRY * DIN; i += stride) {
            float4 v = *(const float4*)(query + i);
            ushort4 o;
            o.x = f2bf(v.x); o.y = f2bf(v.y); o.z = f2bf(v.z); o.w = f2bf(v.w);
            *(ushort4*)(q_bf + i) = o;
        }
    } else if (b < 2560) {                // support f32 -> bf16 (4.2M elems)
        int i = ((b - 2048) * 256 + threadIdx.x) * 4;
        const int stride = 512 * 256 * 4;
        for (; i < NSUP * DIN; i += stride) {
            float4 v = *(const float4*)(support + i);
            ushort4 o;
            o.x = f2bf(v.x); o.y = f2bf(v.y); o.z = f2bf(v.z); o.w = f2bf(v.w);
            *(ushort4*)(s_bf + i) = o;
        }
    } else if (b < 4608) {                // W [DIN][DEMB] f32 -> Wt [DEMB][DIN] bf16
        const int bb = b - 2560;
        const int c0 = (bb & 31) * 32, r0 = (bb >> 5) * 32;
        const int tc = threadIdx.x & 31, tr = threadIdx.x >> 5;
        #pragma unroll
        for (int i = 0; i < 4; i++)
            tile[tr + 8*i][tc] = W[(size_t)(r0 + tr + 8*i) * DEMB + c0 + tc];
        __syncthreads();
        #pragma unroll
        for (int i = 0; i < 4; i++)
            Wt[(size_t)(c0 + tr + 8*i) * DIN + r0 + tc] = f2bf(tile[tc][tr + 8*i]);
    } else {                              // zero proto_sums (65536 f) + qsq (16384 f)
        const int off = ((b - 4608) * 256 + threadIdx.x) * 4;
        float4 z = { 0.f, 0.f, 0.f, 0.f };
        if (off < NWAY * DEMB) *(float4*)(proto_sums + off) = z;
        else                   *(float4*)(qsq + off - NWAY * DEMB) = z;
    }
}

// ================ query GEMM: 256x256, BK=64, 8-wave, 8-PHASE (r17/r18, verified) ====
// 108us, MfmaUtil 25.4%, absmax 0.25, 0 bank conflicts. Full race audit in r17.

#define SG_LO(la, g) { GLL((g), (la)); GLL((g) + 16, (la) + 4096); }
#define SG_HI(la, g) { GLL((g) + 32, (la) + 8192); GLL((g) + 48, (la) + 12288); }

#define READ_B(buf, ks)                                                                \
    _Pragma("unroll") for (int ni = 0; ni < 4; ++ni)                                   \
        bfm[ni] = *(const bf16x8*)&Bs[(buf) * 16384 + (ks) * 8192 + bbase + ni * 128];
#define READ_A(buf, ks, mh)                                                            \
    _Pragma("unroll") for (int mi = 0; mi < 4; ++mi)                                   \
        af[mi] = *(const bf16x8*)&As[(buf) * 16384 + (ks) * 8192 + abase + ((mh)*4 + mi) * 128];
#define MFMA16(mh)                                                                     \
    __builtin_amdgcn_s_setprio(1);                                                     \
    _Pragma("unroll") for (int mi = 0; mi < 4; ++mi)                                   \
        _Pragma("unroll") for (int ni = 0; ni < 4; ++ni)                               \
            acc[(mh)*4 + mi][ni] = __builtin_amdgcn_mfma_f32_16x16x32_bf16(            \
                af[mi], bfm[ni], acc[(mh)*4 + mi][ni], 0, 0, 0);                       \
    __builtin_amdgcn_s_setprio(0);

#define BAR1_LG() do { asm volatile("" ::: "memory"); __builtin_amdgcn_s_barrier();    \
    asm volatile("s_waitcnt lgkmcnt(0)" ::: "memory");                                 \
    __builtin_amdgcn_sched_barrier(0); } while (0)
#define BAR2() do { asm volatile("" ::: "memory"); __builtin_amdgcn_s_barrier();       \
    asm volatile("" ::: "memory"); } while (0)
#define BAR2_VM4() do { asm volatile("s_waitcnt vmcnt(4)" ::: "memory");               \
    __builtin_amdgcn_s_barrier(); asm volatile("" ::: "memory"); } while (0)
#define BAR2_VM0() do { asm volatile("s_waitcnt vmcnt(0)" ::: "memory");               \
    __builtin_amdgcn_s_barrier(); asm volatile("" ::: "memory"); } while (0)

__global__ __launch_bounds__(512) void gemm_query8(
    const unsigned short* __restrict__ A,
    const unsigned short* __restrict__ Bt,
    const float* __restrict__ bias,
    unsigned short* __restrict__ emb_out,
    float* __restrict__ qsq)
{
    __shared__ __attribute__((aligned(16))) unsigned short As[2 * 16384];
    __shared__ __attribute__((aligned(16))) unsigned short Bs[2 * 16384];

    const int tid = threadIdx.x;
    const int nblk = DEMB / 256;          // 4
    const int h = blockIdx.x;
    const int cpx = (int)(gridDim.x >> 3);
    const int wg = (h & 7) * cpx + (h >> 3);
    const int bx = wg % nblk, by = wg / nblk;
    const int brow = by * 256, bcol = bx * 256;
    const int lane = tid & 63, wid = tid >> 6;
    const int wr = wid >> 2, wc = wid & 3;

    const int rows = tid & 255, kg0 = tid >> 8;
    const unsigned short* gA = A  + (size_t)(brow + rows) * DIN + kg0 * 8;
    const unsigned short* gB = Bt + (size_t)(bcol + rows) * DIN + kg0 * 8;
    unsigned short* laA0 = As + tid * 8;
    unsigned short* laA1 = As + 16384 + tid * 8;
    unsigned short* laB0 = Bs + tid * 8;
    unsigned short* laB1 = Bs + 16384 + tid * 8;

    const int kgl = lane >> 4, r = lane & 15;
    const int abase = (kgl * 256 + wr * 128 + r) * 8;
    const int bbase = (kgl * 256 + wc * 64 + r) * 8;

    f32x4 acc[8][4];
    #pragma unroll
    for (int i = 0; i < 8; i++)
        #pragma unroll
        for (int j = 0; j < 4; j++) acc[i][j] = (f32x4)(0.f);

    SG_LO(laA0, gA); SG_LO(laB0, gB);
    SG_HI(laA0, gA); SG_HI(laB0, gB);
    asm volatile("s_waitcnt vmcnt(4)" ::: "memory");
    __builtin_amdgcn_s_barrier();
    asm volatile("" ::: "memory");

    const unsigned short* gA1 = gA + 64;
    const unsigned short* gB1 = gB + 64;
    const unsigned short* gA0 = gA + 128;
    const unsigned short* gB0 = gB + 128;

    bf16x8 af[4], bfm[4];

#define PH_ITER(LAST)                                                                  \
    READ_B(0, 0); READ_A(0, 0, 0); SG_LO(laA1, gA1); BAR1_LG(); MFMA16(0); BAR2();     \
    READ_A(0, 0, 1); SG_LO(laB1, gB1); BAR1_LG(); MFMA16(1); BAR2_VM4();               \
    READ_B(0, 1); READ_A(0, 1, 0); SG_HI(laA1, gA1); BAR1_LG(); MFMA16(0); BAR2();     \
    READ_A(0, 1, 1); SG_HI(laB1, gB1); BAR1_LG(); MFMA16(1); BAR2_VM4();               \
    READ_B(1, 0); READ_A(1, 0, 0);                                                     \
    if (!(LAST)) { SG_LO(laA0, gA0); }                                                 \
    BAR1_LG(); MFMA16(0); BAR2();                                                      \
    READ_A(1, 0, 1);                                                                   \
    if (!(LAST)) { SG_LO(laB0, gB0); }                                                 \
    BAR1_LG(); MFMA16(1);                                                              \
    if (LAST) { BAR2_VM0(); } else { BAR2_VM4(); }                                     \
    READ_B(1, 1); READ_A(1, 1, 0);                                                     \
    if (!(LAST)) { SG_HI(laA0, gA0); }                                                 \
    BAR1_LG(); MFMA16(0); BAR2();                                                      \
    READ_A(1, 1, 1);                                                                   \
    if (!(LAST)) { SG_HI(laB0, gB0); }                                                 \
    BAR1_LG(); MFMA16(1);                                                              \
    if (LAST) { BAR2(); } else { BAR2_VM4(); }

    #pragma unroll 1
    for (int it = 0; it < 15; ++it) {
        PH_ITER(false);
        gA1 += 128; gB1 += 128; gA0 += 128; gB0 += 128;
    }
    PH_ITER(true);
#undef PH_ITER

    const int r16 = lane & 15, quad = lane >> 4;
    float bv[4];
    #pragma unroll
    for (int ni = 0; ni < 4; ni++) bv[ni] = bias[bcol + wc * 64 + ni * 16 + r16];

    #pragma unroll
    for (int mi = 0; mi < 8; mi++) {
        float s0 = 0.f, s1 = 0.f, s2 = 0.f, s3 = 0.f;
        #pragma unroll
        for (int j = 0; j < 4; j++) {
            int row = brow + wr * 128 + mi * 16 + quad * 4 + j;
            float sj = 0.f;
            #pragma unroll
            for (int ni = 0; ni < 4; ni++) {
                float e = acc[mi][ni][j] + bv[ni];
                emb_out[(size_t)row * DEMB + bcol + wc * 64 + ni * 16 + r16] = f2bf(e);
                sj += e * e;
            }
            if (j == 0) s0 = sj; else if (j == 1) s1 = sj; else if (j == 2) s2 = sj; else s3 = sj;
        }
        float sv[4] = { s0, s1, s2, s3 };
        #pragma unroll
        for (int j = 0; j < 4; j++) {
            float v = sv[j];
            v += __shfl_xor(v, 1);
            v += __shfl_xor(v, 2);
            v += __shfl_xor(v, 4);
            v += __shfl_xor(v, 8);
            if (r16 == 0) {
                int row = brow + wr * 128 + mi * 16 + quad * 4 + j;
                atomicAdd(&qsq[row], v);
            }
        }
    }
}

// ---------------- support GEMM: BM=64, BN=128, 3-buf single-barrier (r18, verified) ---
__global__ __launch_bounds__(256, 2) void gemm_support(
    const unsigned short* __restrict__ A,
    const unsigned short* __restrict__ Bt,
    const float* __restrict__ bias,
    const int* __restrict__ labels,
    float* __restrict__ proto_sums)
{
    constexpr int ASZ = 4 * 64 * 8;       // 2048 elems / buf
    constexpr int BSZ = 4 * 128 * 8;      // 4096 elems / buf
    __shared__ __attribute__((aligned(16))) unsigned short AsF[3 * ASZ];
    __shared__ __attribute__((aligned(16))) unsigned short BsF[3 * BSZ];

    const int tid = threadIdx.x;
    const int nblk = DEMB / 128;          // 8
    const int h = blockIdx.x;
    const int cpx = (int)(gridDim.x >> 3);
    const int wg = (h & 7) * cpx + (h >> 3);
    const int bx = wg % nblk, by = wg / nblk;
    const int brow = by * 64, bcol = bx * 128;
    const int lane = tid & 63, wid = tid >> 6;
    const int wc = wid;                   // 1M x 4N

    const unsigned short* ga = A  + (size_t)(brow + (tid & 63)) * DIN + (tid >> 6) * 8;
    const unsigned short* gb = Bt + (size_t)(bcol + (tid & 127)) * DIN + (tid >> 7) * 8;

    f32x4 acc[4][2];
    #pragma unroll
    for (int i = 0; i < 4; i++)
        #pragma unroll
        for (int j = 0; j < 2; j++) acc[i][j] = (f32x4)(0.f);

    auto stageAB = [&](int buf) {
        unsigned short* la = AsF + buf * ASZ + tid * 8;
        unsigned short* lb = BsF + buf * BSZ + tid * 8;
        GLL(ga, la);
        GLL(gb, lb); GLL(gb + 16, lb + 2048);
        ga += 32; gb += 32;
    };

    stageAB(0);

    const int kg = lane >> 4, r = lane & 15;
    const int NT = DIN / 32;   // 64
    int cur = 0, nxt = 1;
    for (int t = 0; t < NT; ++t) {
        if (t < NT - 1) {
            stageAB(nxt);
            asm volatile("s_waitcnt vmcnt(3)" ::: "memory");
        } else {
            asm volatile("s_waitcnt vmcnt(0)" ::: "memory");
        }
        __builtin_amdgcn_s_barrier();
        asm volatile("" ::: "memory");

        const unsigned short* Ab = AsF + cur * ASZ;
        const unsigned short* Bb = BsF + cur * BSZ;
        bf16x8 af[4], bfm[2];
        #pragma unroll
        for (int mi = 0; mi < 4; mi++)
            af[mi] = *(const bf16x8*)&Ab[(kg * 64 + mi * 16 + r) * 8];
        #pragma unroll
        for (int ni = 0; ni < 2; ni++)
            bfm[ni] = *(const bf16x8*)&Bb[(kg * 128 + wc * 32 + ni * 16 + r) * 8];
        __builtin_amdgcn_s_setprio(1);
        #pragma unroll
        for (int mi = 0; mi < 4; mi++)
            #pragma unroll
            for (int ni = 0; ni < 2; ni++)
                acc[mi][ni] = __builtin_amdgcn_mfma_f32_16x16x32_bf16(af[mi], bfm[ni], acc[mi][ni], 0, 0, 0);
        __builtin_amdgcn_s_setprio(0);
        asm volatile("" ::: "memory");

        cur = (cur == 2) ? 0 : cur + 1;
        nxt = (nxt == 2) ? 0 : nxt + 1;
    }

    const int r16 = lane & 15, quad = lane >> 4;
    float bv[2];
    #pragma unroll
    for (int ni = 0; ni < 2; ni++) bv[ni] = bias[bcol + wc * 32 + ni * 16 + r16];

    #pragma unroll
    for (int mi = 0; mi < 4; mi++) {
        #pragma unroll
        for (int j = 0; j < 4; j++) {
            int row = brow + mi * 16 + quad * 4 + j;
            int lab = labels[row];
            #pragma unroll
            for (int ni = 0; ni < 2; ni++) {
                float e = acc[mi][ni][j] + bv[ni];
                atomicAdd(&proto_sums[(size_t)lab * DEMB + bcol + wc * 32 + ni * 16 + r16], e);
            }
        }
    }
}

// ---------------- prototype normalize ----------------
__global__ void proto_norm(const float* __restrict__ proto_sums,
                           const int* __restrict__ labels,
                           unsigned short* __restrict__ proto_bf16,
                           float* __restrict__ psq) {
    int c = blockIdx.x;
    int tid = threadIdx.x;
    int cnt = 0;
    for (int i = tid; i < NSUP; i += 256) cnt += (labels[i] == c) ? 1 : 0;
    #pragma unroll
    for (int m = 1; m < 64; m <<= 1) cnt += __shfl_xor(cnt, m);
    __shared__ int warp_cnt[4];
    __shared__ float warp_ss[4];
    if ((tid & 63) == 0) warp_cnt[tid >> 6] = cnt;
    __syncthreads();
    int total = warp_cnt[0] + warp_cnt[1] + warp_cnt[2] + warp_cnt[3];
    float inv = 1.0f / (float)total;
    float ss = 0.f;
    for (int j = tid; j < DEMB; j += 256) {
        float p = proto_sums[(size_t)c * DEMB + j] * inv;
        proto_bf16[(size_t)c * DEMB + j] = f2bf(p);
        ss += p * p;
    }
    #pragma unroll
    for (int m = 1; m < 64; m <<= 1) ss += __shfl_xor(ss, m);
    if ((tid & 63) == 0) warp_ss[tid >> 6] = ss;
    __syncthreads();
    if (tid == 0) psq[c] = warp_ss[0] + warp_ss[1] + warp_ss[2] + warp_ss[3];
}

// ---------------- scores: out[q][c] = -sqrt(max(qsq+psq-2*dot,0)) ----------------
__global__ __launch_bounds__(256) void scores_kernel(
    const unsigned short* __restrict__ q_emb,
    const unsigned short* __restrict__ protos,
    const float* __restrict__ qsq, const float* __restrict__ psq,
    float* __restrict__ out)
{
    int tid = threadIdx.x, lane = tid & 63, wid = tid >> 6;
    int q0 = blockIdx.x * 64 + wid * 16;
    int r = lane & 15, quad = lane >> 4;
    f32x4 acc[4];
    #pragma unroll
    for (int i = 0; i < 4; i++) acc[i] = (f32x4)(0.f);
    const unsigned short* arow = q_emb + (size_t)(q0 + r) * DEMB + quad * 8;
    for (int k0 = 0; k0 < DEMB; k0 += 32) {
        bf16x8 a = *(const bf16x8*)(arow + k0);
        #pragma unroll
        for (int ni = 0; ni < 4; ni++) {
            bf16x8 bfrag = *(const bf16x8*)(protos + (size_t)(ni * 16 + r) * DEMB + k0 + quad * 8);
            acc[ni] = __builtin_amdgcn_mfma_f32_16x16x32_bf16(a, bfrag, acc[ni], 0, 0, 0);
        }
    }
    #pragma unroll
    for (int ni = 0; ni < 4; ni++) {
        int c = ni * 16 + r;
        float ps = psq[c];
        #pragma unroll
        for (int j = 0; j < 4; j++) {
            int row = q0 + quad * 4 + j;
            float d2 = qsq[row] + ps - 2.0f * acc[ni][j];
            d2 = fmaxf(d2, 0.0f);
            out[(size_t)row * NWAY + c] = -sqrtf(d2);
        }
    }
}

// ---------------- launch ----------------
extern "C" void kernel_launch(void* const* d_in, const int* in_sizes, int n_in,
                              void* d_out, int out_size, void* d_ws, size_t ws_size,
                              hipStream_t stream) {
    const float* support = (const float*)d_in[0];
    const float* query   = (const float*)d_in[1];
    const int*   labels  = (const int*)d_in[2];
    // d_in[3] = n_way (assumed 64)
    const float* W       = (const float*)d_in[4];
    const float* bias    = (const float*)d_in[5];
    float* out = (float*)d_out;

    char* ws = (char*)d_ws;
    unsigned short* q_bf     = (unsigned short*)(ws);                 // 67108864 B
    unsigned short* s_bf     = (unsigned short*)(ws + 67108864);      //  8388608 B
    unsigned short* Wt       = (unsigned short*)(ws + 75497472);      //  4194304 B
    unsigned short* q_emb    = (unsigned short*)(ws + 79691776);      // 33554432 B
    float*          proto_sums = (float*)(ws + 113246208);            //   262144 B
    unsigned short* proto_bf = (unsigned short*)(ws + 113508352);     //   131072 B
    float*          qsq      = (float*)(ws + 113639424);              //    65536 B
    float*          psq      = (float*)(ws + 113704960);              //      256 B

    // prep: [0,2048) query cvt | [2048,2560) support cvt | [2560,4608) W transpose
    //       | [4608,4688) zero proto_sums+qsq
    prep_kernel<<<4688, 256, 0, stream>>>(query, support, W, q_bf, s_bf, Wt,
                                          proto_sums, qsq);
    gemm_support<<<(NSUP / 64) * (DEMB / 128), 256, 0, stream>>>(
        s_bf, Wt, bias, labels, proto_sums);
    proto_norm<<<NWAY, 256, 0, stream>>>(proto_sums, labels, proto_bf, psq);
    gemm_query8<<<(NQRY / 256) * (DEMB / 256), 512, 0, stream>>>(
        q_bf, Wt, bias, q_emb, qsq);
    scores_kernel<<<NQRY / 64, 256, 0, stream>>>(q_emb, proto_bf, qsq, psq, out);
}